// Round 12
// baseline (199.617 us; speedup 1.0000x reference)
//
#include <hip/hip_runtime.h>
#include <cstdint>

typedef __bf16 bf16x8 __attribute__((ext_vector_type(8)));
typedef float f32x4 __attribute__((ext_vector_type(4)));
typedef unsigned short u16;
typedef unsigned int u32;

__device__ __forceinline__ u16 f2bf(float f) {
    u32 u = __builtin_bit_cast(u32, f);
    u += 0x7fffu + ((u >> 16) & 1u);
    return (u16)(u >> 16);
}

__device__ __forceinline__ float bf2f(u32 x) {
    return __builtin_bit_cast(float, x << 16);
}

__device__ __forceinline__ void gl_lds16(const u16* g, u16* l) {
    __builtin_amdgcn_global_load_lds(
        (const __attribute__((address_space(1))) void*)g,
        (__attribute__((address_space(3))) void*)l,
        16, 0, 0);
}

__device__ __forceinline__ f32x4 mfma16(bf16x8 a, bf16x8 b, f32x4 c) {
    return __builtin_amdgcn_mfma_f32_16x16x32_bf16(a, b, c, 0, 0, 0);
}

// Micro-tiled layout for bf16 intermediates: [col/16][row/4][4][16].
// idx(row,col) = ((col>>4)*(M>>2) + (row>>2))*64 + (row&3)*16 + (col&15)
// V^T buffer (per batch): idx = b*98304 + ((t>>4)*256 + (ch>>2))*64 + (ch&3)*16 + (t&15)

// ---------------- fp32 -> bf16 conversions (single merged dispatch) -------
struct CvtAll {
    const float* s[6];
    u16* d[6];
    int srcn[6];
    int totn[6];
    int off[6];
};

__global__ void cvt_all(CvtAll a) {
    const int blk = blockIdx.x;
    int seg = 0;
#pragma unroll
    for (int s = 1; s < 6; ++s) seg += (blk >= a.off[s]);
    const int i = ((blk - a.off[seg]) * 256 + threadIdx.x) * 4;
    if (i >= a.totn[seg]) return;
    float4 v = make_float4(0.f, 0.f, 0.f, 0.f);
    if (i < a.srcn[seg]) v = *(const float4*)&a.s[seg][i];
    ushort4 o;
    o.x = f2bf(v.x); o.y = f2bf(v.y); o.z = f2bf(v.z); o.w = f2bf(v.w);
    *(ushort4*)&a.d[seg][i] = o;
}

// ---------------- big GEMM: 256x128 tile, BK=32, 3-slot ring, 2 blk/CU ----
__device__ __forceinline__ void store_out(u16* C, long idx, float v) { C[idx] = f2bf(v); }
__device__ __forceinline__ void store_out(float* C, long idx, float v) { C[idx] = v; }

template <typename OutT, bool BA, bool BC>
__global__ __launch_bounds__(512, 2) void gemmP(
    const u16* __restrict__ A, const u16* __restrict__ W,
    const float* __restrict__ bias, OutT* __restrict__ C,
    int M, int N, int K) {
    __shared__ __align__(16) u16 As[3][256 * 32];  // 3 x 16KB
    __shared__ __align__(16) u16 Bs[3][128 * 32];  // 3 x 8KB

    const int tid = threadIdx.x;
    const int wid = tid >> 6, l = tid & 63;
    const int wr = wid >> 1, wc = wid & 1;        // 4 M-waves x 2 N-waves
    const int l15 = l & 15, lg = l >> 4;

    const int lin = blockIdx.y * gridDim.x + blockIdx.x;
    const int cpx = (gridDim.x * gridDim.y) >> 3;
    const int swz = (lin & 7) * cpx + (lin >> 3);
    const long tn = swz & 7;
    const long tm = swz >> 3;

    const int srp = tid >> 3;
    const int sv = (tid & 7) ^ (srp & 7);
    const int sE = (sv >> 2) & 1;
    const int sKC = sv & 3;
    const long ar0 = tm * 256 + 2 * srp + sE;
    const long brow = tn * 128 + 2 * srp + sE;
    const long aRB = ar0 >> 2;
    const int aSub = (int)(ar0 & 3) * 16 + (sKC & 1) * 8;
    const int aCB = sKC >> 1;

    const int NT = K >> 5;

#define STAGE(s_, t_)                                                          \
    do {                                                                       \
        if (BA) {                                                              \
            const long cb_ = (long)((t_) * 2 + aCB) * (M >> 2);                \
            gl_lds16(A + (cb_ + aRB) * 64 + aSub, &As[s_][tid * 8]);           \
            gl_lds16(A + (cb_ + aRB + 32) * 64 + aSub,                         \
                     &As[s_][4096 + tid * 8]);                                 \
        } else {                                                               \
            gl_lds16(A + ar0 * (long)K + (t_) * 32 + sKC * 8,                  \
                     &As[s_][tid * 8]);                                        \
            gl_lds16(A + (ar0 + 128) * (long)K + (t_) * 32 + sKC * 8,          \
                     &As[s_][4096 + tid * 8]);                                 \
        }                                                                      \
        gl_lds16(W + brow * (long)K + (t_) * 32 + sKC * 8,                     \
                 &Bs[s_][tid * 8]);                                            \
    } while (0)

    const int e = l15 & 1;
    const int rphA = wr * 32 + (l15 >> 1);
    const int rphB = wc * 32 + (l15 >> 1);
    const int pA = ((e * 4 + lg) ^ (rphA & 7)) * 8;
    const int pB = ((e * 4 + lg) ^ (rphB & 7)) * 8;
    const int aOff = rphA * 64 + pA;
    const int bOff = rphB * 64 + pB;

    f32x4 acc[4][4] = {};

    STAGE(0, 0);
    STAGE(1, 1);

    for (int t = 0; t < NT; ++t) {
        if (t + 1 < NT)
            asm volatile("s_waitcnt vmcnt(3)" ::: "memory");
        else
            asm volatile("s_waitcnt vmcnt(0)" ::: "memory");
        __builtin_amdgcn_sched_barrier(0);
        __builtin_amdgcn_s_barrier();

        if (t + 2 < NT) {
            const int ns = (t + 2) % 3;
            STAGE(ns, t + 2);
        }

        const int c = t % 3;
        bf16x8 a[4], b[4];
#pragma unroll
        for (int nf = 0; nf < 4; ++nf)
            b[nf] = *(const bf16x8*)&Bs[c][bOff + nf * 512];
#pragma unroll
        for (int mf = 0; mf < 4; ++mf)
            a[mf] = *(const bf16x8*)&As[c][aOff + mf * 512];

        __builtin_amdgcn_s_setprio(1);
#pragma unroll
        for (int mf = 0; mf < 4; ++mf)
#pragma unroll
            for (int nf = 0; nf < 4; ++nf)
                acc[mf][nf] = mfma16(a[mf], b[nf], acc[mf][nf]);
        __builtin_amdgcn_s_setprio(0);
    }
#undef STAGE

    const long row0 = tm * 256 + wr * 64;
    const long col0 = tn * 128 + wc * 64;
    float bv[4];
#pragma unroll
    for (int nf = 0; nf < 4; ++nf) bv[nf] = bias[col0 + nf * 16 + l15];
    if (BC) {
        const long ct0 = col0 >> 4;
        const long rb = row0 >> 2;
#pragma unroll
        for (int mf = 0; mf < 4; ++mf)
#pragma unroll
            for (int nf = 0; nf < 4; ++nf)
#pragma unroll
                for (int r = 0; r < 4; ++r) {
                    const long idx =
                        ((ct0 + nf) * (long)(M >> 2) + rb + mf * 4 + lg) * 64 +
                        r * 16 + l15;
                    store_out(C, idx, acc[mf][nf][r] + bv[nf]);
                }
    } else {
#pragma unroll
        for (int mf = 0; mf < 4; ++mf)
#pragma unroll
            for (int nf = 0; nf < 4; ++nf)
#pragma unroll
                for (int r = 0; r < 4; ++r) {
                    const long row = row0 + mf * 16 + lg * 4 + r;
                    const long col = col0 + nf * 16 + l15;
                    store_out(C, row * N + col, acc[mf][nf][r] + bv[nf]);
                }
    }
}

// ---------------- small GEMM for K/V projections: dbuf + XOR-8 swizzle ----
template <bool VT>
__device__ __forceinline__ void gemm128_body(
    const u16* __restrict__ A, const u16* __restrict__ W,
    const float* __restrict__ bias, u16* __restrict__ C,
    int N, int K) {
    __shared__ __align__(16) u16 As[2][128 * 64];  // 2 x 16KB
    __shared__ __align__(16) u16 Bs[2][128 * 64];
    const int tid = threadIdx.x;
    const int w = tid >> 6, l = tid & 63;
    const int wr = w >> 1, wc = w & 1;
    const int l15 = l & 15, lg = l >> 4;
    const long tm = blockIdx.y, tn = blockIdx.x;
    const u16* Ab = A + tm * 128 * (long)K;
    const u16* Bb = W + tn * 128 * (long)K;

    const int srow = tid >> 3;                 // 0..31
    const int skc = (tid & 7) ^ (srow & 7);    // pre-swizzled source chunk

#define KV_STAGE(s_, k0_)                                                     \
    do {                                                                      \
        _Pragma("unroll")                                                     \
        for (int j_ = 0; j_ < 4; ++j_) {                                      \
            gl_lds16(Ab + (long)(srow + j_ * 32) * K + (k0_) + skc * 8,       \
                     &As[s_][j_ * 2048 + tid * 8]);                           \
            gl_lds16(Bb + (long)(srow + j_ * 32) * K + (k0_) + skc * 8,       \
                     &Bs[s_][j_ * 2048 + tid * 8]);                           \
        }                                                                     \
    } while (0)

    f32x4 acc[4][4] = {};
    const int NT = K >> 6;

    KV_STAGE(0, 0);
    __syncthreads();

    for (int t = 0; t < NT; ++t) {
        const int c = t & 1;
        if (t + 1 < NT) KV_STAGE(c ^ 1, (t + 1) << 6);

#pragma unroll
        for (int kk = 0; kk < 2; ++kk) {
            bf16x8 a[4], bb[4];
#pragma unroll
            for (int m = 0; m < 4; ++m) {
                const int ar = wr * 64 + m * 16 + l15;
                const int cc = (kk * 4 + lg) ^ (ar & 7);
                a[m] = *(const bf16x8*)&As[c][ar * 64 + cc * 8];
            }
#pragma unroll
            for (int n = 0; n < 4; ++n) {
                const int br = wc * 64 + n * 16 + l15;
                const int cc = (kk * 4 + lg) ^ (br & 7);
                bb[n] = *(const bf16x8*)&Bs[c][br * 64 + cc * 8];
            }
#pragma unroll
            for (int m = 0; m < 4; ++m)
#pragma unroll
                for (int n = 0; n < 4; ++n)
                    acc[m][n] = mfma16(a[m], bb[n], acc[m][n]);
        }
        __syncthreads();
    }
#undef KV_STAGE

    const long row0 = tm * 128 + wr * 64;
    const long col0 = tn * 128 + wc * 64;
#pragma unroll
    for (int m = 0; m < 4; ++m)
#pragma unroll
        for (int n = 0; n < 4; ++n)
#pragma unroll
            for (int r = 0; r < 4; ++r) {
                const float v = acc[m][n][r] + bias[col0 + n * 16 + l15];
                if (VT) {
                    const int row = (int)(row0 + m * 16 + lg * 4 + r);  // enc row
                    if (row < 308) {
                        const int bb = row / 77;
                        const int t = row - bb * 77;
                        const int ch = (int)(col0 + n * 16 + l15);
                        const long idx = (long)bb * 98304 +
                                         ((long)(t >> 4) * 256 + (ch >> 2)) * 64 +
                                         (ch & 3) * 16 + (t & 15);
                        C[idx] = f2bf(v);
                    }
                } else {
                    const long idx = (((col0 >> 4) + n) * 96L + (row0 >> 2) + m * 4 + lg) * 64 +
                                     r * 16 + l15;
                    C[idx] = f2bf(v);
                }
            }
}

__global__ __launch_bounds__(256) void gemm_kv(
    const u16* __restrict__ A,
    const u16* __restrict__ Wk, const float* __restrict__ bk, u16* __restrict__ Ko,
    const u16* __restrict__ Wv, const float* __restrict__ bv, u16* __restrict__ Vo,
    int N, int K) {
    if (blockIdx.z == 0)
        gemm128_body<false>(A, Wk, bk, Ko, N, K);
    else
        gemm128_body<true>(A, Wv, bv, Vo, N, K);
}

// ---------------- fused attention (swapped QK^T, mask staged in LDS) ------
__global__ __launch_bounds__(256, 3) void attn_fused(
    const u16* __restrict__ Q,    // [16384,1024] micro-tiled
    const u16* __restrict__ Kb,   // [384,1024] micro-tiled
    const u16* __restrict__ Vt,   // V^T per-batch transposed
    const float* __restrict__ mask,  // [B,4096,77] f32
    u16* __restrict__ Ao) {          // [16384,1024] micro-tiled
    __shared__ u16 Ps[128 * 104];    // 26.0 KB
    __shared__ u16 Ms[128 * 88];     // 22.0 KB bf16 mask, stride 88, t>=77 = -1e38

    const int h = blockIdx.x, b = blockIdx.y, nt = blockIdx.z;
    const int tid = threadIdx.x;
    const int w = tid >> 6, l = tid & 63;
    const int l15 = l & 15, lg = l >> 4;

    // ---- stage mask tile (coalesced, dependency-free) ----
    {
        const float* mb = mask + ((long)b * 4096 + nt * 128) * 77;
        const int lane = tid & 63;
        const int rg = tid >> 6;  // 4 rows per pass
#pragma unroll
        for (int g = 0; g < 32; ++g) {
            const int row = g * 4 + rg;
            const long rb = (long)row * 77;
            Ms[row * 88 + lane] = f2bf(mb[rb + lane]);
            const int t2 = lane + 64;
            if (t2 < 80) {
                const float v1 = (t2 < 77) ? mb[rb + t2] : -1e38f;
                Ms[row * 88 + t2] = f2bf(v1);
            }
        }
    }
    __syncthreads();

    const int qrow = b * 4096 + nt * 128 + w * 32;

    // ---- QK^T (swapped: A=K rows, B=Q rows), t-cols 0..79 ----
    f32x4 acc[5][2] = {};
#pragma unroll
    for (int kk = 0; kk < 64; kk += 32) {
        const int d = kk + lg * 8;
        const int cb = h * 4 + (d >> 4);
        const int dlow = d & 15;
        bf16x8 kf[5], qf[2];
#pragma unroll
        for (int n = 0; n < 5; ++n) {
            const int row = b * 77 + n * 16 + l15;
            kf[n] = *(const bf16x8*)&Kb[((long)cb * 96 + (row >> 2)) * 64 +
                                        (row & 3) * 16 + dlow];
        }
#pragma unroll
        for (int m = 0; m < 2; ++m) {
            const int row = qrow + m * 16 + l15;
            qf[m] = *(const bf16x8*)&Q[((long)cb * 4096 + (row >> 2)) * 64 +
                                       (row & 3) * 16 + dlow];
        }
#pragma unroll
        for (int n = 0; n < 5; ++n)
#pragma unroll
            for (int m = 0; m < 2; ++m)
                acc[n][m] = mfma16(kf[n], qf[m], acc[n][m]);
    }

    // ---- softmax per q (mask from LDS, in-lane over t + 2 shfl_xor) ----
#pragma unroll
    for (int m = 0; m < 2; ++m) {
        const int lrow = w * 32 + m * 16 + l15;
        float vals[5][4];
        float rmax = -3e38f;
#pragma unroll
        for (int n = 0; n < 5; ++n) {
            const uint2 mm = *(const uint2*)&Ms[lrow * 88 + n * 16 + lg * 4];
            const float mv0 = bf2f(mm.x & 0xffffu);
            const float mv1 = bf2f(mm.x >> 16);
            const float mv2 = bf2f(mm.y & 0xffffu);
            const float mv3 = bf2f(mm.y >> 16);
            vals[n][0] = fmaf(acc[n][m][0], 0.125f, mv0);
            vals[n][1] = fmaf(acc[n][m][1], 0.125f, mv1);
            vals[n][2] = fmaf(acc[n][m][2], 0.125f, mv2);
            vals[n][3] = fmaf(acc[n][m][3], 0.125f, mv3);
#pragma unroll
            for (int r = 0; r < 4; ++r) rmax = fmaxf(rmax, vals[n][r]);
        }
        rmax = fmaxf(rmax, __shfl_xor(rmax, 16, 64));
        rmax = fmaxf(rmax, __shfl_xor(rmax, 32, 64));
        float s = 0.f;
#pragma unroll
        for (int n = 0; n < 5; ++n)
#pragma unroll
            for (int r = 0; r < 4; ++r) {
                const float e = __expf(vals[n][r] - rmax);
                vals[n][r] = e;
                s += e;
            }
        s += __shfl_xor(s, 16, 64);
        s += __shfl_xor(s, 32, 64);
        const float inv = 1.f / s;
#pragma unroll
        for (int n = 0; n < 5; ++n) {
            const u32 lo = (u32)f2bf(vals[n][0] * inv) |
                           ((u32)f2bf(vals[n][1] * inv) << 16);
            const u32 hi = (u32)f2bf(vals[n][2] * inv) |
                           ((u32)f2bf(vals[n][3] * inv) << 16);
            *(uint2*)&Ps[(w * 32 + m * 16 + l15) * 104 + n * 16 + lg * 4] =
                make_uint2(lo, hi);
        }
        *(uint2*)&Ps[(w * 32 + m * 16 + l15) * 104 + 80 + lg * 4] = make_uint2(0, 0);
    }

    // ---- PV: A = P rows (LDS), B = V^T rows (global) ----
    f32x4 o[2][4] = {};
#pragma unroll
    for (int kt = 0; kt < 96; kt += 32) {
        bf16x8 pa[2], vf[4];
#pragma unroll
        for (int m = 0; m < 2; ++m)
            pa[m] = *(const bf16x8*)&Ps[(w * 32 + m * 16 + l15) * 104 + kt + lg * 8];
        const int t0 = kt + lg * 8;
#pragma unroll
        for (int n = 0; n < 4; ++n) {
            const int ch = h * 64 + n * 16 + l15;
            vf[n] = *(const bf16x8*)&Vt[(long)b * 98304 +
                                        ((long)(t0 >> 4) * 256 + (ch >> 2)) * 64 +
                                        (ch & 3) * 16 + (t0 & 15)];
        }
#pragma unroll
        for (int m = 0; m < 2; ++m)
#pragma unroll
            for (int n = 0; n < 4; ++n)
                o[m][n] = mfma16(pa[m], vf[n], o[m][n]);
    }

#pragma unroll
    for (int m = 0; m < 2; ++m)
#pragma unroll
        for (int n = 0; n < 4; ++n)
#pragma unroll
            for (int r = 0; r < 4; ++r) {
                const long idx = ((long)(h * 4 + n) * 4096 +
                                  b * 1024 + nt * 32 + w * 8 + m * 4 + lg) * 64 +
                                 r * 16 + l15;
                Ao[idx] = f2bf(o[m][n][r]);
            }
}

// ---------------- launch ----------------------------------------------------
extern "C" void kernel_launch(void* const* d_in, const int* in_sizes, int n_in,
                              void* d_out, int out_size, void* d_ws, size_t ws_size,
                              hipStream_t stream) {
    const float* hidden = (const float*)d_in[0];
    const float* enc = (const float*)d_in[1];
    const float* mask = (const float*)d_in[2];
    const float* Wq = (const float*)d_in[3];
    const float* bq = (const float*)d_in[4];
    const float* Wk = (const float*)d_in[5];
    const float* bk = (const float*)d_in[6];
    const float* Wv = (const float*)d_in[7];
    const float* bv = (const float*)d_in[8];
    const float* Wo = (const float*)d_in[9];
    const float* bo = (const float*)d_in[10];
    float* out = (float*)d_out;

    char* ws = (char*)d_ws;
    u16* hiddenB = (u16*)(ws);                       // 32 MB
    u16* Qb = (u16*)(ws + 33554432L);                // 32 MB
    u16* AoB = (u16*)(ws + 2 * 33554432L);           // 32 MB
    u16* WqB = (u16*)(ws + 3 * 33554432L);           // 2 MB each
    u16* WkB = WqB + 1048576;
    u16* WvB = WkB + 1048576;
    u16* WoB = WvB + 1048576;
    u16* encB = WoB + 1048576;                       // 384*1024 bf16
    u16* Kbuf = encB + 393216;
    u16* VtBuf = Kbuf + 393216;                      // 4 x 98304 u16

    CvtAll ca;
    ca.s[0] = hidden; ca.d[0] = hiddenB; ca.srcn[0] = 16777216; ca.totn[0] = 16777216;
    ca.s[1] = Wq;  ca.d[1] = WqB; ca.srcn[1] = 1048576; ca.totn[1] = 1048576;
    ca.s[2] = Wk;  ca.d[2] = WkB; ca.srcn[2] = 1048576; ca.totn[2] = 1048576;
    ca.s[3] = Wv;  ca.d[3] = WvB; ca.srcn[3] = 1048576; ca.totn[3] = 1048576;
    ca.s[4] = Wo;  ca.d[4] = WoB; ca.srcn[4] = 1048576; ca.totn[4] = 1048576;
    ca.s[5] = enc; ca.d[5] = encB; ca.srcn[5] = 315392; ca.totn[5] = 393216;
    ca.off[0] = 0;
    ca.off[1] = 16384;
    ca.off[2] = 17408;
    ca.off[3] = 18432;
    ca.off[4] = 19456;
    ca.off[5] = 20480;
    cvt_all<<<dim3(20864), 256, 0, stream>>>(ca);

    // projections
    gemmP<u16, false, true><<<dim3(8, 64), 512, 0, stream>>>(
        hiddenB, WqB, bq, Qb, 16384, 1024, 1024);
    gemm_kv<<<dim3(8, 3, 2), 256, 0, stream>>>(encB, WkB, bk, Kbuf, WvB, bv, VtBuf, 1024, 1024);

    attn_fused<<<dim3(16, 4, 32), 256, 0, stream>>>(Qb, Kbuf, VtBuf, mask, AoB);

    gemmP<float, true, false><<<dim3(8, 64), 512, 0, stream>>>(
        AoB, WoB, bo, out, 16384, 1024, 1024);
}

// Round 13
// 161.365 us; speedup vs baseline: 1.2371x; 1.2371x over previous
//
#include <hip/hip_runtime.h>
#include <cstdint>

typedef __bf16 bf16x8 __attribute__((ext_vector_type(8)));
typedef float f32x4 __attribute__((ext_vector_type(4)));
typedef unsigned short u16;
typedef unsigned int u32;

__device__ __forceinline__ u16 f2bf(float f) {
    u32 u = __builtin_bit_cast(u32, f);
    u += 0x7fffu + ((u >> 16) & 1u);
    return (u16)(u >> 16);
}

__device__ __forceinline__ float bf2f(u32 x) {
    return __builtin_bit_cast(float, x << 16);
}

__device__ __forceinline__ void gl_lds16(const u16* g, u16* l) {
    __builtin_amdgcn_global_load_lds(
        (const __attribute__((address_space(1))) void*)g,
        (__attribute__((address_space(3))) void*)l,
        16, 0, 0);
}

__device__ __forceinline__ f32x4 mfma16(bf16x8 a, bf16x8 b, f32x4 c) {
    return __builtin_amdgcn_mfma_f32_16x16x32_bf16(a, b, c, 0, 0, 0);
}

// Micro-tiled layout for bf16 intermediates: [col/16][row/4][4][16].
// idx(row,col) = ((col>>4)*(M>>2) + (row>>2))*64 + (row&3)*16 + (col&15)
// V^T buffer (per batch): idx = b*98304 + ((t>>4)*256 + (ch>>2))*64 + (ch&3)*16 + (t&15)
// maskB: [b*4096+q][80] bf16, t>=77 = -1e38 (8B-aligned uint2 reads at t0=4k).

// ---------------- fp32 -> bf16 conversions (single merged dispatch) -------
struct CvtAll {
    const float* s[6];
    u16* d[6];
    int srcn[6];
    int totn[6];
    int off[6];
};

__global__ void cvt_all(CvtAll a) {
    const int blk = blockIdx.x;
    int seg = 0;
#pragma unroll
    for (int s = 1; s < 6; ++s) seg += (blk >= a.off[s]);
    const int i = ((blk - a.off[seg]) * 256 + threadIdx.x) * 4;
    if (i >= a.totn[seg]) return;
    float4 v = make_float4(0.f, 0.f, 0.f, 0.f);
    if (i < a.srcn[seg]) v = *(const float4*)&a.s[seg][i];
    ushort4 o;
    o.x = f2bf(v.x); o.y = f2bf(v.y); o.z = f2bf(v.z); o.w = f2bf(v.w);
    *(ushort4*)&a.d[seg][i] = o;
}

// ---------------- mask f32[*,77] -> bf16[*,80] padded with -1e38 ----------
__global__ void cvt_mask(const float* __restrict__ mask, u16* __restrict__ maskB) {
    const int j = (blockIdx.x * 256 + threadIdx.x) * 4;   // 4 u16 out / thread
    if (j >= 1310720) return;                             // 16384 * 80
    const int row = j / 80;
    const int t0 = j - row * 80;                          // multiple of 4
    const long src = (long)row * 77 + t0;
    const u16 pad = f2bf(-1e38f);
    ushort4 o;
    o.x = f2bf(mask[src]);
    o.y = (t0 + 1 < 77) ? f2bf(mask[src + 1]) : pad;
    o.z = (t0 + 2 < 77) ? f2bf(mask[src + 2]) : pad;
    o.w = (t0 + 3 < 77) ? f2bf(mask[src + 3]) : pad;
    *(ushort4*)&maskB[j] = o;
}

// ---------------- big GEMM: 256x128 tile, BK=32, 3-slot ring, 2 blk/CU ----
__device__ __forceinline__ void store_out(u16* C, long idx, float v) { C[idx] = f2bf(v); }
__device__ __forceinline__ void store_out(float* C, long idx, float v) { C[idx] = v; }

template <typename OutT, bool BA, bool BC>
__global__ __launch_bounds__(512, 2) void gemmP(
    const u16* __restrict__ A, const u16* __restrict__ W,
    const float* __restrict__ bias, OutT* __restrict__ C,
    int M, int N, int K) {
    __shared__ __align__(16) u16 As[3][256 * 32];  // 3 x 16KB
    __shared__ __align__(16) u16 Bs[3][128 * 32];  // 3 x 8KB

    const int tid = threadIdx.x;
    const int wid = tid >> 6, l = tid & 63;
    const int wr = wid >> 1, wc = wid & 1;        // 4 M-waves x 2 N-waves
    const int l15 = l & 15, lg = l >> 4;

    const int lin = blockIdx.y * gridDim.x + blockIdx.x;
    const int cpx = (gridDim.x * gridDim.y) >> 3;
    const int swz = (lin & 7) * cpx + (lin >> 3);
    const long tn = swz & 7;
    const long tm = swz >> 3;

    const int srp = tid >> 3;
    const int sv = (tid & 7) ^ (srp & 7);
    const int sE = (sv >> 2) & 1;
    const int sKC = sv & 3;
    const long ar0 = tm * 256 + 2 * srp + sE;
    const long brow = tn * 128 + 2 * srp + sE;
    const long aRB = ar0 >> 2;
    const int aSub = (int)(ar0 & 3) * 16 + (sKC & 1) * 8;
    const int aCB = sKC >> 1;

    const int NT = K >> 5;

#define STAGE(s_, t_)                                                          \
    do {                                                                       \
        if (BA) {                                                              \
            const long cb_ = (long)((t_) * 2 + aCB) * (M >> 2);                \
            gl_lds16(A + (cb_ + aRB) * 64 + aSub, &As[s_][tid * 8]);           \
            gl_lds16(A + (cb_ + aRB + 32) * 64 + aSub,                         \
                     &As[s_][4096 + tid * 8]);                                 \
        } else {                                                               \
            gl_lds16(A + ar0 * (long)K + (t_) * 32 + sKC * 8,                  \
                     &As[s_][tid * 8]);                                        \
            gl_lds16(A + (ar0 + 128) * (long)K + (t_) * 32 + sKC * 8,          \
                     &As[s_][4096 + tid * 8]);                                 \
        }                                                                      \
        gl_lds16(W + brow * (long)K + (t_) * 32 + sKC * 8,                     \
                 &Bs[s_][tid * 8]);                                            \
    } while (0)

    const int e = l15 & 1;
    const int rphA = wr * 32 + (l15 >> 1);
    const int rphB = wc * 32 + (l15 >> 1);
    const int pA = ((e * 4 + lg) ^ (rphA & 7)) * 8;
    const int pB = ((e * 4 + lg) ^ (rphB & 7)) * 8;
    const int aOff = rphA * 64 + pA;
    const int bOff = rphB * 64 + pB;

    f32x4 acc[4][4] = {};

    STAGE(0, 0);
    STAGE(1, 1);

    for (int t = 0; t < NT; ++t) {
        if (t + 1 < NT)
            asm volatile("s_waitcnt vmcnt(3)" ::: "memory");
        else
            asm volatile("s_waitcnt vmcnt(0)" ::: "memory");
        __builtin_amdgcn_sched_barrier(0);
        __builtin_amdgcn_s_barrier();

        if (t + 2 < NT) {
            const int ns = (t + 2) % 3;
            STAGE(ns, t + 2);
        }

        const int c = t % 3;
        bf16x8 a[4], b[4];
#pragma unroll
        for (int nf = 0; nf < 4; ++nf)
            b[nf] = *(const bf16x8*)&Bs[c][bOff + nf * 512];
#pragma unroll
        for (int mf = 0; mf < 4; ++mf)
            a[mf] = *(const bf16x8*)&As[c][aOff + mf * 512];

        __builtin_amdgcn_s_setprio(1);
#pragma unroll
        for (int mf = 0; mf < 4; ++mf)
#pragma unroll
            for (int nf = 0; nf < 4; ++nf)
                acc[mf][nf] = mfma16(a[mf], b[nf], acc[mf][nf]);
        __builtin_amdgcn_s_setprio(0);
    }
#undef STAGE

    const long row0 = tm * 256 + wr * 64;
    const long col0 = tn * 128 + wc * 64;
    float bv[4];
#pragma unroll
    for (int nf = 0; nf < 4; ++nf) bv[nf] = bias[col0 + nf * 16 + l15];
    if (BC) {
        const long ct0 = col0 >> 4;
        const long rb = row0 >> 2;
#pragma unroll
        for (int mf = 0; mf < 4; ++mf)
#pragma unroll
            for (int nf = 0; nf < 4; ++nf)
#pragma unroll
                for (int r = 0; r < 4; ++r) {
                    const long idx =
                        ((ct0 + nf) * (long)(M >> 2) + rb + mf * 4 + lg) * 64 +
                        r * 16 + l15;
                    store_out(C, idx, acc[mf][nf][r] + bv[nf]);
                }
    } else {
#pragma unroll
        for (int mf = 0; mf < 4; ++mf)
#pragma unroll
            for (int nf = 0; nf < 4; ++nf)
#pragma unroll
                for (int r = 0; r < 4; ++r) {
                    const long row = row0 + mf * 16 + lg * 4 + r;
                    const long col = col0 + nf * 16 + l15;
                    store_out(C, row * N + col, acc[mf][nf][r] + bv[nf]);
                }
    }
}

// ---------------- small GEMM for K/V projections: dbuf + XOR-8 swizzle ----
template <bool VT>
__device__ __forceinline__ void gemm128_body(
    const u16* __restrict__ A, const u16* __restrict__ W,
    const float* __restrict__ bias, u16* __restrict__ C,
    int N, int K) {
    __shared__ __align__(16) u16 As[2][128 * 64];  // 2 x 16KB
    __shared__ __align__(16) u16 Bs[2][128 * 64];
    const int tid = threadIdx.x;
    const int w = tid >> 6, l = tid & 63;
    const int wr = w >> 1, wc = w & 1;
    const int l15 = l & 15, lg = l >> 4;
    const long tm = blockIdx.y, tn = blockIdx.x;
    const u16* Ab = A + tm * 128 * (long)K;
    const u16* Bb = W + tn * 128 * (long)K;

    const int srow = tid >> 3;                 // 0..31
    const int skc = (tid & 7) ^ (srow & 7);    // pre-swizzled source chunk

#define KV_STAGE(s_, k0_)                                                     \
    do {                                                                      \
        _Pragma("unroll")                                                     \
        for (int j_ = 0; j_ < 4; ++j_) {                                      \
            gl_lds16(Ab + (long)(srow + j_ * 32) * K + (k0_) + skc * 8,       \
                     &As[s_][j_ * 2048 + tid * 8]);                           \
            gl_lds16(Bb + (long)(srow + j_ * 32) * K + (k0_) + skc * 8,       \
                     &Bs[s_][j_ * 2048 + tid * 8]);                           \
        }                                                                     \
    } while (0)

    f32x4 acc[4][4] = {};
    const int NT = K >> 6;

    KV_STAGE(0, 0);
    __syncthreads();

    for (int t = 0; t < NT; ++t) {
        const int c = t & 1;
        if (t + 1 < NT) KV_STAGE(c ^ 1, (t + 1) << 6);

#pragma unroll
        for (int kk = 0; kk < 2; ++kk) {
            bf16x8 a[4], bb[4];
#pragma unroll
            for (int m = 0; m < 4; ++m) {
                const int ar = wr * 64 + m * 16 + l15;
                const int cc = (kk * 4 + lg) ^ (ar & 7);
                a[m] = *(const bf16x8*)&As[c][ar * 64 + cc * 8];
            }
#pragma unroll
            for (int n = 0; n < 4; ++n) {
                const int br = wc * 64 + n * 16 + l15;
                const int cc = (kk * 4 + lg) ^ (br & 7);
                bb[n] = *(const bf16x8*)&Bs[c][br * 64 + cc * 8];
            }
#pragma unroll
            for (int m = 0; m < 4; ++m)
#pragma unroll
                for (int n = 0; n < 4; ++n)
                    acc[m][n] = mfma16(a[m], bb[n], acc[m][n]);
        }
        __syncthreads();
    }
#undef KV_STAGE

    const long row0 = tm * 128 + wr * 64;
    const long col0 = tn * 128 + wc * 64;
#pragma unroll
    for (int m = 0; m < 4; ++m)
#pragma unroll
        for (int n = 0; n < 4; ++n)
#pragma unroll
            for (int r = 0; r < 4; ++r) {
                const float v = acc[m][n][r] + bias[col0 + n * 16 + l15];
                if (VT) {
                    const int row = (int)(row0 + m * 16 + lg * 4 + r);  // enc row
                    if (row < 308) {
                        const int bb = row / 77;
                        const int t = row - bb * 77;
                        const int ch = (int)(col0 + n * 16 + l15);
                        const long idx = (long)bb * 98304 +
                                         ((long)(t >> 4) * 256 + (ch >> 2)) * 64 +
                                         (ch & 3) * 16 + (t & 15);
                        C[idx] = f2bf(v);
                    }
                } else {
                    const long idx = (((col0 >> 4) + n) * 96L + (row0 >> 2) + m * 4 + lg) * 64 +
                                     r * 16 + l15;
                    C[idx] = f2bf(v);
                }
            }
}

__global__ __launch_bounds__(256) void gemm_kv(
    const u16* __restrict__ A,
    const u16* __restrict__ Wk, const float* __restrict__ bk, u16* __restrict__ Ko,
    const u16* __restrict__ Wv, const float* __restrict__ bv, u16* __restrict__ Vo,
    int N, int K) {
    if (blockIdx.z == 0)
        gemm128_body<false>(A, Wk, bk, Ko, N, K);
    else
        gemm128_body<true>(A, Wv, bv, Vo, N, K);
}

// ---------------- fused attention (global-direct, swapped QK^T) -----------
// Mask read from precomputed padded bf16 maskB (uint2, 8B aligned).
__global__ __launch_bounds__(256, 4) void attn_fused(
    const u16* __restrict__ Q,    // [16384,1024] micro-tiled
    const u16* __restrict__ Kb,   // [384,1024] micro-tiled
    const u16* __restrict__ Vt,   // V^T per-batch transposed
    const u16* __restrict__ maskB,  // [16384,80] bf16, pad=-1e38
    u16* __restrict__ Ao) {          // [16384,1024] micro-tiled
    __shared__ u16 Ps[128 * 104];

    const int h = blockIdx.x, b = blockIdx.y, nt = blockIdx.z;
    const int tid = threadIdx.x;
    const int w = tid >> 6, l = tid & 63;
    const int l15 = l & 15, lg = l >> 4;

    const int qrow = b * 4096 + nt * 128 + w * 32;

    // ---- QK^T (swapped: A=K rows, B=Q rows), t-cols 0..79 ----
    f32x4 acc[5][2] = {};
#pragma unroll
    for (int kk = 0; kk < 64; kk += 32) {
        const int d = kk + lg * 8;
        const int cb = h * 4 + (d >> 4);
        const int dlow = d & 15;
        bf16x8 kf[5], qf[2];
#pragma unroll
        for (int n = 0; n < 5; ++n) {
            const int row = b * 77 + n * 16 + l15;
            kf[n] = *(const bf16x8*)&Kb[((long)cb * 96 + (row >> 2)) * 64 +
                                        (row & 3) * 16 + dlow];
        }
#pragma unroll
        for (int m = 0; m < 2; ++m) {
            const int row = qrow + m * 16 + l15;
            qf[m] = *(const bf16x8*)&Q[((long)cb * 4096 + (row >> 2)) * 64 +
                                       (row & 3) * 16 + dlow];
        }
#pragma unroll
        for (int n = 0; n < 5; ++n)
#pragma unroll
            for (int m = 0; m < 2; ++m)
                acc[n][m] = mfma16(kf[n], qf[m], acc[n][m]);
    }

    // ---- softmax per q (mask via 5 uint2 loads; in-lane over t) ----
#pragma unroll
    for (int m = 0; m < 2; ++m) {
        const long mrow = ((long)qrow + m * 16 + l15) * 80;
        float vals[5][4];
        float rmax = -3e38f;
#pragma unroll
        for (int n = 0; n < 5; ++n) {
            const uint2 mm = *(const uint2*)&maskB[mrow + n * 16 + lg * 4];
            vals[n][0] = fmaf(acc[n][m][0], 0.125f, bf2f(mm.x & 0xffffu));
            vals[n][1] = fmaf(acc[n][m][1], 0.125f, bf2f(mm.x >> 16));
            vals[n][2] = fmaf(acc[n][m][2], 0.125f, bf2f(mm.y & 0xffffu));
            vals[n][3] = fmaf(acc[n][m][3], 0.125f, bf2f(mm.y >> 16));
#pragma unroll
            for (int r = 0; r < 4; ++r) rmax = fmaxf(rmax, vals[n][r]);
        }
        rmax = fmaxf(rmax, __shfl_xor(rmax, 16, 64));
        rmax = fmaxf(rmax, __shfl_xor(rmax, 32, 64));
        float s = 0.f;
#pragma unroll
        for (int n = 0; n < 5; ++n)
#pragma unroll
            for (int r = 0; r < 4; ++r) {
                const float e = __expf(vals[n][r] - rmax);
                vals[n][r] = e;
                s += e;
            }
        s += __shfl_xor(s, 16, 64);
        s += __shfl_xor(s, 32, 64);
        const float inv = 1.f / s;
#pragma unroll
        for (int n = 0; n < 5; ++n) {
            const u32 lo = (u32)f2bf(vals[n][0] * inv) |
                           ((u32)f2bf(vals[n][1] * inv) << 16);
            const u32 hi = (u32)f2bf(vals[n][2] * inv) |
                           ((u32)f2bf(vals[n][3] * inv) << 16);
            *(uint2*)&Ps[(w * 32 + m * 16 + l15) * 104 + n * 16 + lg * 4] =
                make_uint2(lo, hi);
        }
        *(uint2*)&Ps[(w * 32 + m * 16 + l15) * 104 + 80 + lg * 4] = make_uint2(0, 0);
    }

    // ---- PV: A = P rows (LDS), B = V^T rows (global) ----
    f32x4 o[2][4] = {};
#pragma unroll
    for (int kt = 0; kt < 96; kt += 32) {
        bf16x8 pa[2], vf[4];
#pragma unroll
        for (int m = 0; m < 2; ++m)
            pa[m] = *(const bf16x8*)&Ps[(w * 32 + m * 16 + l15) * 104 + kt + lg * 8];
        const int t0 = kt + lg * 8;
#pragma unroll
        for (int n = 0; n < 4; ++n) {
            const int ch = h * 64 + n * 16 + l15;
            vf[n] = *(const bf16x8*)&Vt[(long)b * 98304 +
                                        ((long)(t0 >> 4) * 256 + (ch >> 2)) * 64 +
                                        (ch & 3) * 16 + (t0 & 15)];
        }
#pragma unroll
        for (int m = 0; m < 2; ++m)
#pragma unroll
            for (int n = 0; n < 4; ++n)
                o[m][n] = mfma16(pa[m], vf[n], o[m][n]);
    }

#pragma unroll
    for (int m = 0; m < 2; ++m)
#pragma unroll
        for (int n = 0; n < 4; ++n)
#pragma unroll
            for (int r = 0; r < 4; ++r) {
                const long idx = ((long)(h * 4 + n) * 4096 +
                                  b * 1024 + nt * 32 + w * 8 + m * 4 + lg) * 64 +
                                 r * 16 + l15;
                Ao[idx] = f2bf(o[m][n][r]);
            }
}

// ---------------- launch ----------------------------------------------------
extern "C" void kernel_launch(void* const* d_in, const int* in_sizes, int n_in,
                              void* d_out, int out_size, void* d_ws, size_t ws_size,
                              hipStream_t stream) {
    const float* hidden = (const float*)d_in[0];
    const float* enc = (const float*)d_in[1];
    const float* mask = (const float*)d_in[2];
    const float* Wq = (const float*)d_in[3];
    const float* bq = (const float*)d_in[4];
    const float* Wk = (const float*)d_in[5];
    const float* bk = (const float*)d_in[6];
    const float* Wv = (const float*)d_in[7];
    const float* bv = (const float*)d_in[8];
    const float* Wo = (const float*)d_in[9];
    const float* bo = (const float*)d_in[10];
    float* out = (float*)d_out;

    char* ws = (char*)d_ws;
    u16* hiddenB = (u16*)(ws);                       // 32 MB
    u16* Qb = (u16*)(ws + 33554432L);                // 32 MB
    u16* AoB = (u16*)(ws + 2 * 33554432L);           // 32 MB
    u16* WqB = (u16*)(ws + 3 * 33554432L);           // 2 MB each
    u16* WkB = WqB + 1048576;
    u16* WvB = WkB + 1048576;
    u16* WoB = WvB + 1048576;
    u16* encB = WoB + 1048576;                       // 384*1024 bf16
    u16* Kbuf = encB + 393216;
    u16* VtBuf = Kbuf + 393216;                      // 4 x 98304 u16
    u16* maskBuf = VtBuf + 393216;                   // 16384 x 80 u16 (2.62 MB)

    CvtAll ca;
    ca.s[0] = hidden; ca.d[0] = hiddenB; ca.srcn[0] = 16777216; ca.totn[0] = 16777216;
    ca.s[1] = Wq;  ca.d[1] = WqB; ca.srcn[1] = 1048576; ca.totn[1] = 1048576;
    ca.s[2] = Wk;  ca.d[2] = WkB; ca.srcn[2] = 1048576; ca.totn[2] = 1048576;
    ca.s[3] = Wv;  ca.d[3] = WvB; ca.srcn[3] = 1048576; ca.totn[3] = 1048576;
    ca.s[4] = Wo;  ca.d[4] = WoB; ca.srcn[4] = 1048576; ca.totn[4] = 1048576;
    ca.s[5] = enc; ca.d[5] = encB; ca.srcn[5] = 315392; ca.totn[5] = 393216;
    ca.off[0] = 0;
    ca.off[1] = 16384;
    ca.off[2] = 17408;
    ca.off[3] = 18432;
    ca.off[4] = 19456;
    ca.off[5] = 20480;
    cvt_all<<<dim3(20864), 256, 0, stream>>>(ca);
    cvt_mask<<<dim3(1280), 256, 0, stream>>>(mask, maskBuf);

    // projections
    gemmP<u16, false, true><<<dim3(8, 64), 512, 0, stream>>>(
        hiddenB, WqB, bq, Qb, 16384, 1024, 1024);
    gemm_kv<<<dim3(8, 3, 2), 256, 0, stream>>>(encB, WkB, bk, Kbuf, WvB, bv, VtBuf, 1024, 1024);

    attn_fused<<<dim3(16, 4, 32), 256, 0, stream>>>(Qb, Kbuf, VtBuf, maskBuf, AoB);

    gemmP<float, true, false><<<dim3(8, 64), 512, 0, stream>>>(
        AoB, WoB, bo, out, 16384, 1024, 1024);
}